// Round 3
// baseline (709.460 us; speedup 1.0000x reference)
//
#include <hip/hip_runtime.h>
#include <math.h>

#define N_PTS 65536
#define M_IND 1024
#define KNN 16
#define JITTER 1e-4f

// Packed lower-triangular Su: P[i*(i+1)/2 + j], j <= i.
#define PACKED_FLOATS (M_IND * (M_IND + 1) / 2)               // 524800
#define PACKED_BYTES  ((size_t)PACKED_FLOATS * sizeof(float)) // 2,099,200 B

// ---------------------------------------------------------------------------
// Kernel A: packed Su = tril(Lu Lu^T), Lu = tril(Lu_raw,-1)+diag(exp(diag)).
// Triangular 32x32 tiles (528 blocks), k-loop bounded by j0+32 (Lu lower-tri).
// Writes ONLY j <= i into the packed array -> never exceeds PACKED_BYTES of
// d_ws, and no racing writes at all.
// ---------------------------------------------------------------------------
#define TSU 32
#define BKSU 16
#define SU_BLOCKS 528   // 32*33/2 triangular tiles

__global__ __launch_bounds__(256) void su_kernel(const float* __restrict__ Lu_raw,
                                                 float* __restrict__ P) {
    __shared__ float As[TSU][BKSU + 1];
    __shared__ float Bs[TSU][BKSU + 1];

    int bid = blockIdx.x;
    int rt = (int)((sqrtf(8.0f * (float)bid + 1.0f) - 1.0f) * 0.5f);
    while ((rt + 1) * (rt + 2) / 2 <= bid) ++rt;
    while (rt * (rt + 1) / 2 > bid) --rt;
    int ct = bid - rt * (rt + 1) / 2;   // ct <= rt
    int i0 = rt * TSU, j0 = ct * TSU;

    int tid = threadIdx.x;
    int tx = tid & 15, ty = tid >> 4;   // 16x16 threads, each 2x2 outputs
    float acc00 = 0.f, acc01 = 0.f, acc10 = 0.f, acc11 = 0.f;

    int kmax = j0 + TSU;                // k <= min(i,j) <= j0+31
    for (int k0 = 0; k0 < kmax; k0 += BKSU) {
        #pragma unroll
        for (int t = 0; t < 2; ++t) {
            int e = tid + t * 256;      // 512 elements per tile
            int r = e >> 4, c = e & 15;
            int gi = i0 + r, gk = k0 + c;
            float v = Lu_raw[gi * M_IND + gk];
            As[r][c] = (gk < gi) ? v : ((gk == gi) ? __expf(v) : 0.0f);
            int gj = j0 + r;
            float w = Lu_raw[gj * M_IND + gk];
            Bs[r][c] = (gk < gj) ? w : ((gk == gj) ? __expf(w) : 0.0f);
        }
        __syncthreads();
        #pragma unroll
        for (int kk = 0; kk < BKSU; ++kk) {
            float a0 = As[ty][kk], a1 = As[ty + 16][kk];
            float b0 = Bs[tx][kk], b1 = Bs[tx + 16][kk];
            acc00 = fmaf(a0, b0, acc00);
            acc01 = fmaf(a0, b1, acc01);
            acc10 = fmaf(a1, b0, acc10);
            acc11 = fmaf(a1, b1, acc11);
        }
        __syncthreads();
    }

    int i_a = i0 + ty, i_b = i0 + ty + 16;
    int j_a = j0 + tx, j_b = j0 + tx + 16;
    if (j_a <= i_a) P[((unsigned)i_a * (i_a + 1) >> 1) + j_a] = acc00;
    if (j_b <= i_a) P[((unsigned)i_a * (i_a + 1) >> 1) + j_b] = acc01;
    if (j_a <= i_b) P[((unsigned)i_b * (i_b + 1) >> 1) + j_a] = acc10;
    if (j_b <= i_b) P[((unsigned)i_b * (i_b + 1) >> 1) + j_b] = acc11;
}

// ---------------------------------------------------------------------------
// Kernel B: per-point 16-NN selection + local GP solve.
// USE_WS=true : qs from packed Su gathers (fast path).
// USE_WS=false: qs recomputed on demand from Lu_raw (no workspace; safety
//               fallback if ws_size < PACKED_BYTES).
// ---------------------------------------------------------------------------
template <bool USE_WS>
__global__ __launch_bounds__(256, 1) void vnngp_kernel(const float* __restrict__ X,
                                                       const float* __restrict__ Z,
                                                       const float* __restrict__ mu,
                                                       const float* __restrict__ P,
                                                       const float* __restrict__ Lu_raw,
                                                       float* __restrict__ out) {
    __shared__ float4 Zs[M_IND];   // x,y,z,|z|^2  (16 KB)
    __shared__ float mus[M_IND];   // 4 KB
    int tid = threadIdx.x;
    for (int r = tid; r < M_IND; r += 256) {
        float zx = Z[r * 3 + 0], zy = Z[r * 3 + 1], zz = Z[r * 3 + 2];
        Zs[r] = make_float4(zx, zy, zz, zx * zx + zy * zy + zz * zz);
        mus[r] = mu[r];
    }
    __syncthreads();

    int n = blockIdx.x * 256 + tid;
    float x0 = X[n * 3 + 0], x1 = X[n * 3 + 1], x2 = X[n * 3 + 2];
    float xq = x0 * x0 + x1 * x1 + x2 * x2;

    // ---- Phase 1: exact top-16 smallest squared distances ----
    // key = (f32 bits of dist) << 32 | index : u64 order == (dist, index) order
    unsigned long long key[KNN];
    #pragma unroll
    for (int j = 0; j < KNN; ++j) key[j] = ~0ULL;

    for (int m = 0; m < M_IND; ++m) {
        float4 z = Zs[m];
        float dot = x0 * z.x + x1 * z.y + x2 * z.z;
        float d = fmaxf(xq + z.w - 2.0f * dot, 0.0f);
        unsigned long long kk =
            ((unsigned long long)__float_as_uint(d) << 32) | (unsigned)m;
        if (kk < key[KNN - 1]) {
            #pragma unroll
            for (int j = 0; j < KNN; ++j) {
                unsigned long long t = key[j];
                bool c = kk < t;
                key[j] = c ? kk : t;
                kk = c ? t : kk;
            }
        }
    }

    // ---- Phase 2: local GP ----
    int idx[KNN];
    float kv[KNN];
    float nx[KNN], ny[KNN], nz[KNN], nq[KNN];
    #pragma unroll
    for (int a = 0; a < KNN; ++a) {
        idx[a] = (int)(key[a] & 0xFFFFFFFFULL);
        float d = __uint_as_float((unsigned)(key[a] >> 32));
        kv[a] = __expf(-0.5f * d);            // lKxz entries
        float4 z = Zs[idx[a]];
        nx[a] = z.x; ny[a] = z.y; nz[a] = z.z; nq[a] = z.w;
    }

    // A = lKzz + JITTER*I, lower triangle; lKzz diag already carries the
    // global jitter from Kzz_j = L L^T  ->  diag = 1 + 2*JITTER.
    float A[KNN * (KNN + 1) / 2];
    #pragma unroll
    for (int r = 0; r < KNN; ++r) {
        A[r * (r + 1) / 2 + r] = 1.0f + 2.0f * JITTER;
        #pragma unroll
        for (int c = 0; c < r; ++c) {
            float dd = nq[r] + nq[c]
                     - 2.0f * (nx[r] * nx[c] + ny[r] * ny[c] + nz[r] * nz[c]);
            dd = fmaxf(dd, 0.0f);
            A[r * (r + 1) / 2 + c] = __expf(-0.5f * dd);
        }
    }

    // In-place Cholesky; store 1/L[c][c] in the diagonal slot.
    #pragma unroll
    for (int c = 0; c < KNN; ++c) {
        float diag = A[c * (c + 1) / 2 + c];
        #pragma unroll
        for (int k = 0; k < c; ++k) {
            float l = A[c * (c + 1) / 2 + k];
            diag = fmaf(-l, l, diag);
        }
        float s = sqrtf(fmaxf(diag, 1e-12f));
        float rinv = 1.0f / s;
        A[c * (c + 1) / 2 + c] = rinv;
        #pragma unroll
        for (int r = c + 1; r < KNN; ++r) {
            float v = A[r * (r + 1) / 2 + c];
            #pragma unroll
            for (int k = 0; k < c; ++k)
                v = fmaf(-A[r * (r + 1) / 2 + k], A[c * (c + 1) / 2 + k], v);
            A[r * (r + 1) / 2 + c] = v * rinv;
        }
    }

    // Solve A w = kv  (forward then backward); y aliases w.
    float w[KNN];
    #pragma unroll
    for (int r = 0; r < KNN; ++r) {
        float v = kv[r];
        #pragma unroll
        for (int c = 0; c < r; ++c) v = fmaf(-A[r * (r + 1) / 2 + c], w[c], v);
        w[r] = v * A[r * (r + 1) / 2 + r];
    }
    #pragma unroll
    for (int r = KNN - 1; r >= 0; --r) {
        float v = w[r];
        #pragma unroll
        for (int c = r + 1; c < KNN; ++c) v = fmaf(-A[c * (c + 1) / 2 + r], w[c], v);
        w[r] = v * A[r * (r + 1) / 2 + r];
    }

    // W lKzz W^T = w.k - JITTER*||w||^2   (since A w = k, lKzz = A - JITTER*I)
    float wk = 0.f, ww = 0.f, mean = 0.f;
    #pragma unroll
    for (int a = 0; a < KNN; ++a) {
        wk = fmaf(w[a], kv[a], wk);
        ww = fmaf(w[a], w[a], ww);
        mean = fmaf(w[a], mus[idx[a]], mean);
    }

    // qs = w^T Su[idx,idx] w
    float qs = 0.f;
    if (USE_WS) {
        // 136 symmetric gathers from packed lower-tri Su (L2-resident)
        #pragma unroll
        for (int r = 0; r < KNN; ++r) {
            int a = idx[r];
            float wr = w[r];
            float rowacc = 0.f;
            #pragma unroll
            for (int c = 0; c < r; ++c) {
                int b = idx[c];
                int hi = a > b ? a : b;
                int lo = a > b ? b : a;
                rowacc = fmaf(w[c], P[((unsigned)hi * (hi + 1) >> 1) + lo], rowacc);
            }
            qs = fmaf(wr, fmaf(wr, P[((unsigned)a * (a + 1) >> 1) + a], 2.0f * rowacc), qs);
        }
    } else {
        // On-demand: qs = sum_k ( sum_a w_a * Lu[idx_a, k] )^2, Lu lower-tri
        // with exp on the diagonal. Sort neighbors by index, sweep k.
        int si[KNN]; float sw[KNN];
        #pragma unroll
        for (int a = 0; a < KNN; ++a) { si[a] = idx[a]; sw[a] = w[a]; }
        #pragma unroll
        for (int a = 1; a < KNN; ++a) {          // insertion sort by index
            int iv = si[a]; float wv = sw[a];
            int b = a - 1;
            while (b >= 0 && si[b] > iv) { si[b + 1] = si[b]; sw[b + 1] = sw[b]; --b; }
            si[b + 1] = iv; sw[b + 1] = wv;
        }
        int s = 0;
        int kend = si[KNN - 1];
        for (int k = 0; k <= kend; ++k) {
            float v = 0.f;
            if (s < KNN && si[s] == k) {
                v = sw[s] * __expf(Lu_raw[(unsigned)k * M_IND + k]);
                ++s;
            }
            for (int a = s; a < KNN; ++a)
                v = fmaf(sw[a], Lu_raw[(unsigned)si[a] * M_IND + k], v);
            qs = fmaf(v, v, qs);
        }
    }

    float cov = 1.0f - (wk - JITTER * ww) + qs;
    float sd = sqrtf(fmaxf(cov, 0.05f));
    out[n] = mean;
    out[N_PTS + n] = sd;
}

// ---------------------------------------------------------------------------
extern "C" void kernel_launch(void* const* d_in, const int* in_sizes, int n_in,
                              void* d_out, int out_size, void* d_ws, size_t ws_size,
                              hipStream_t stream) {
    const float* X      = (const float*)d_in[0];
    const float* Z      = (const float*)d_in[1];
    const float* Lu_raw = (const float*)d_in[2];
    const float* mu     = (const float*)d_in[3];
    float* out = (float*)d_out;

    if (ws_size >= PACKED_BYTES) {
        float* P = (float*)d_ws;   // 2,099,200 B packed lower-tri Su
        su_kernel<<<SU_BLOCKS, 256, 0, stream>>>(Lu_raw, P);
        vnngp_kernel<true><<<N_PTS / 256, 256, 0, stream>>>(X, Z, mu, P, Lu_raw, out);
    } else {
        // ws too small for Su: exact on-demand fallback, touches no workspace.
        vnngp_kernel<false><<<N_PTS / 256, 256, 0, stream>>>(X, Z, mu, nullptr, Lu_raw, out);
    }
}

// Round 4
// 408.612 us; speedup vs baseline: 1.7363x; 1.7363x over previous
//
#include <hip/hip_runtime.h>
#include <math.h>

#define N_PTS 65536
#define M_IND 1024
#define KNN 16
#define JITTER 1e-4f

// Packed lower-triangular Su: P[i*(i+1)/2 + j], j <= i.
#define PACKED_FLOATS (M_IND * (M_IND + 1) / 2)               // 524800
#define PACKED_BYTES  ((size_t)PACKED_FLOATS * sizeof(float)) // 2,099,200 B

// ---------------------------------------------------------------------------
// Kernel A: packed Su = tril(Lu Lu^T), Lu = tril(Lu_raw,-1)+diag(exp(diag)).
// Triangular 32x32 tiles (528 blocks), BK=32 (one barrier pair per 32 k).
// ---------------------------------------------------------------------------
#define TSU 32
#define BKSU 32
#define SU_BLOCKS 528   // 32*33/2 triangular tiles

__global__ __launch_bounds__(256) void su_kernel(const float* __restrict__ Lu_raw,
                                                 float* __restrict__ P) {
    __shared__ float As[TSU][BKSU + 1];
    __shared__ float Bs[TSU][BKSU + 1];

    int bid = blockIdx.x;
    int rt = (int)((sqrtf(8.0f * (float)bid + 1.0f) - 1.0f) * 0.5f);
    while ((rt + 1) * (rt + 2) / 2 <= bid) ++rt;
    while (rt * (rt + 1) / 2 > bid) --rt;
    int ct = bid - rt * (rt + 1) / 2;   // ct <= rt
    int i0 = rt * TSU, j0 = ct * TSU;

    int tid = threadIdx.x;
    int tx = tid & 15, ty = tid >> 4;   // 16x16 threads, each 2x2 outputs
    float acc00 = 0.f, acc01 = 0.f, acc10 = 0.f, acc11 = 0.f;

    int kmax = j0 + TSU;                // k <= min(i,j) <= j0+31
    for (int k0 = 0; k0 < kmax; k0 += BKSU) {
        #pragma unroll
        for (int t = 0; t < 4; ++t) {
            int e = tid + t * 256;      // 1024 elements per tile
            int r = e >> 5, c = e & 31;
            int gi = i0 + r, gk = k0 + c;
            float v = Lu_raw[gi * M_IND + gk];
            As[r][c] = (gk < gi) ? v : ((gk == gi) ? __expf(v) : 0.0f);
            int gj = j0 + r;
            float w = Lu_raw[gj * M_IND + gk];
            Bs[r][c] = (gk < gj) ? w : ((gk == gj) ? __expf(w) : 0.0f);
        }
        __syncthreads();
        #pragma unroll
        for (int kk = 0; kk < BKSU; ++kk) {
            float a0 = As[ty][kk], a1 = As[ty + 16][kk];
            float b0 = Bs[tx][kk], b1 = Bs[tx + 16][kk];
            acc00 = fmaf(a0, b0, acc00);
            acc01 = fmaf(a0, b1, acc01);
            acc10 = fmaf(a1, b0, acc10);
            acc11 = fmaf(a1, b1, acc11);
        }
        __syncthreads();
    }

    int i_a = i0 + ty, i_b = i0 + ty + 16;
    int j_a = j0 + tx, j_b = j0 + tx + 16;
    if (j_a <= i_a) P[((unsigned)i_a * (i_a + 1) >> 1) + j_a] = acc00;
    if (j_b <= i_a) P[((unsigned)i_a * (i_a + 1) >> 1) + j_b] = acc01;
    if (j_a <= i_b) P[((unsigned)i_b * (i_b + 1) >> 1) + j_a] = acc10;
    if (j_b <= i_b) P[((unsigned)i_b * (i_b + 1) >> 1) + j_b] = acc11;
}

// ---------------------------------------------------------------------------
// Kernel B: 4 threads/point selection (4 waves/SIMD for latency hiding) +
// shfl_xor bitonic merge + 1-thread/point local GP solve.
// Block = 512 threads = 128 points. Grid = 512 blocks.
// ---------------------------------------------------------------------------
#define PTS_PER_BLK 128

template <bool USE_WS>
__global__ __launch_bounds__(512, 4) void vnngp_kernel(const float* __restrict__ X,
                                                       const float* __restrict__ Z,
                                                       const float* __restrict__ mu,
                                                       const float* __restrict__ P,
                                                       const float* __restrict__ Lu_raw,
                                                       float* __restrict__ out) {
    __shared__ float4 Zs[M_IND];                              // 16 KB
    __shared__ float mus[M_IND];                              // 4 KB
    __shared__ unsigned long long hand[PTS_PER_BLK][KNN + 1]; // 17 KB (+1 pad)
    int tid = threadIdx.x;
    for (int r = tid; r < M_IND; r += 512) {
        float zx = Z[r * 3 + 0], zy = Z[r * 3 + 1], zz = Z[r * 3 + 2];
        Zs[r] = make_float4(zx, zy, zz, zx * zx + zy * zy + zz * zz);
        mus[r] = mu[r];
    }
    __syncthreads();

    // ---- Phase 1: each of 4 sub-threads scans a 256-candidate stripe ----
    {
        int pt = tid >> 2, sub = tid & 3;
        int n = blockIdx.x * PTS_PER_BLK + pt;
        float x0 = X[n * 3 + 0], x1 = X[n * 3 + 1], x2 = X[n * 3 + 2];
        float xq = x0 * x0 + x1 * x1 + x2 * x2;

        // key = (f32 bits of dist) << 32 | index : u64 order == (dist, index)
        unsigned long long key[KNN];
        #pragma unroll
        for (int j = 0; j < KNN; ++j) key[j] = ~0ULL;

        int mbase = sub << 8;
        float4 z = Zs[mbase];
        for (int i = 0; i < 256; ++i) {
            float4 zn = Zs[mbase + ((i + 1) & 255)];  // prefetch (wraps, unused at i=255)
            float dot = x0 * z.x + x1 * z.y + x2 * z.z;
            float d = fmaxf(xq + z.w - 2.0f * dot, 0.0f);
            unsigned long long kk =
                ((unsigned long long)__float_as_uint(d) << 32) | (unsigned)(mbase + i);
            if (kk < key[KNN - 1]) {
                #pragma unroll
                for (int j = 0; j < KNN; ++j) {
                    unsigned long long t = key[j];
                    bool c = kk < t;
                    key[j] = c ? kk : t;
                    kk = c ? t : kk;
                }
            }
            z = zn;
        }

        // ---- merge 4 sorted-16 lists within each quad (exact set union) ----
        #pragma unroll
        for (int round = 1; round <= 2; round <<= 1) {
            unsigned long long other[KNN];
            #pragma unroll
            for (int i = 0; i < KNN; ++i)
                other[i] = __shfl_xor(key[i], round, 64);
            #pragma unroll
            for (int i = 0; i < KNN; ++i) {           // lowest-16 of 32 (bitonic)
                unsigned long long b = other[KNN - 1 - i];
                key[i] = key[i] < b ? key[i] : b;
            }
            #pragma unroll
            for (int dstep = 8; dstep >= 1; dstep >>= 1) {  // bitonic -> ascending
                #pragma unroll
                for (int i = 0; i < KNN; ++i)
                    if ((i & dstep) == 0) {
                        unsigned long long a = key[i], b = key[i | dstep];
                        key[i] = a < b ? a : b;
                        key[i | dstep] = a < b ? b : a;
                    }
            }
        }
        if (sub == 0) {
            #pragma unroll
            for (int i = 0; i < KNN; ++i) hand[pt][i] = key[i];
        }
    }
    __syncthreads();
    if (tid >= PTS_PER_BLK) return;

    // ---- Phase 2: local GP, one thread per point ----
    int n = blockIdx.x * PTS_PER_BLK + tid;
    int idx[KNN];
    float kv[KNN];
    float nx[KNN], ny[KNN], nz[KNN], nq[KNN];
    #pragma unroll
    for (int a = 0; a < KNN; ++a) {
        unsigned long long k = hand[tid][a];
        idx[a] = (int)(k & 0xFFFFFFFFULL);
        float d = __uint_as_float((unsigned)(k >> 32));
        kv[a] = __expf(-0.5f * d);            // lKxz entries
        float4 z = Zs[idx[a]];
        nx[a] = z.x; ny[a] = z.y; nz[a] = z.z; nq[a] = z.w;
    }

    // A = lKzz + JITTER*I (lower tri); lKzz diag carries global jitter from
    // Kzz_j = L L^T -> diag = 1 + 2*JITTER.
    float A[KNN * (KNN + 1) / 2];
    #pragma unroll
    for (int r = 0; r < KNN; ++r) {
        A[r * (r + 1) / 2 + r] = 1.0f + 2.0f * JITTER;
        #pragma unroll
        for (int c = 0; c < r; ++c) {
            float dd = nq[r] + nq[c]
                     - 2.0f * (nx[r] * nx[c] + ny[r] * ny[c] + nz[r] * nz[c]);
            dd = fmaxf(dd, 0.0f);
            A[r * (r + 1) / 2 + c] = __expf(-0.5f * dd);
        }
    }

    // In-place Cholesky; store 1/L[c][c] in the diagonal slot.
    #pragma unroll
    for (int c = 0; c < KNN; ++c) {
        float diag = A[c * (c + 1) / 2 + c];
        #pragma unroll
        for (int k = 0; k < c; ++k) {
            float l = A[c * (c + 1) / 2 + k];
            diag = fmaf(-l, l, diag);
        }
        float s = sqrtf(fmaxf(diag, 1e-12f));
        float rinv = 1.0f / s;
        A[c * (c + 1) / 2 + c] = rinv;
        #pragma unroll
        for (int r = c + 1; r < KNN; ++r) {
            float v = A[r * (r + 1) / 2 + c];
            #pragma unroll
            for (int k = 0; k < c; ++k)
                v = fmaf(-A[r * (r + 1) / 2 + k], A[c * (c + 1) / 2 + k], v);
            A[r * (r + 1) / 2 + c] = v * rinv;
        }
    }

    // Solve A w = kv (forward then backward).
    float w[KNN];
    #pragma unroll
    for (int r = 0; r < KNN; ++r) {
        float v = kv[r];
        #pragma unroll
        for (int c = 0; c < r; ++c) v = fmaf(-A[r * (r + 1) / 2 + c], w[c], v);
        w[r] = v * A[r * (r + 1) / 2 + r];
    }
    #pragma unroll
    for (int r = KNN - 1; r >= 0; --r) {
        float v = w[r];
        #pragma unroll
        for (int c = r + 1; c < KNN; ++c) v = fmaf(-A[c * (c + 1) / 2 + r], w[c], v);
        w[r] = v * A[r * (r + 1) / 2 + r];
    }

    // W lKzz W^T = w.k - JITTER*||w||^2   (A w = k, lKzz = A - JITTER*I)
    float wk = 0.f, ww = 0.f, mean = 0.f;
    #pragma unroll
    for (int a = 0; a < KNN; ++a) {
        wk = fmaf(w[a], kv[a], wk);
        ww = fmaf(w[a], w[a], ww);
        mean = fmaf(w[a], mus[idx[a]], mean);
    }

    // qs = w^T Su[idx,idx] w
    float qs = 0.f;
    if (USE_WS) {
        #pragma unroll
        for (int r = 0; r < KNN; ++r) {
            int a = idx[r];
            float wr = w[r];
            float rowacc = 0.f;
            #pragma unroll
            for (int c = 0; c < r; ++c) {
                int b = idx[c];
                int hi = a > b ? a : b;
                int lo = a > b ? b : a;
                rowacc = fmaf(w[c], P[((unsigned)hi * (hi + 1) >> 1) + lo], rowacc);
            }
            qs = fmaf(wr, fmaf(wr, P[((unsigned)a * (a + 1) >> 1) + a], 2.0f * rowacc), qs);
        }
    } else {
        // On-demand fallback: qs = sum_k (sum_a w_a * Lu[idx_a, k])^2
        int si[KNN]; float sw[KNN];
        #pragma unroll
        for (int a = 0; a < KNN; ++a) { si[a] = idx[a]; sw[a] = w[a]; }
        #pragma unroll
        for (int a = 1; a < KNN; ++a) {
            int iv = si[a]; float wv = sw[a];
            int b = a - 1;
            while (b >= 0 && si[b] > iv) { si[b + 1] = si[b]; sw[b + 1] = sw[b]; --b; }
            si[b + 1] = iv; sw[b + 1] = wv;
        }
        int s = 0;
        int kend = si[KNN - 1];
        for (int k = 0; k <= kend; ++k) {
            float v = 0.f;
            if (s < KNN && si[s] == k) {
                v = sw[s] * __expf(Lu_raw[(unsigned)k * M_IND + k]);
                ++s;
            }
            for (int a = s; a < KNN; ++a)
                v = fmaf(sw[a], Lu_raw[(unsigned)si[a] * M_IND + k], v);
            qs = fmaf(v, v, qs);
        }
    }

    float cov = 1.0f - (wk - JITTER * ww) + qs;
    float sd = sqrtf(fmaxf(cov, 0.05f));
    out[n] = mean;
    out[N_PTS + n] = sd;
}

// ---------------------------------------------------------------------------
extern "C" void kernel_launch(void* const* d_in, const int* in_sizes, int n_in,
                              void* d_out, int out_size, void* d_ws, size_t ws_size,
                              hipStream_t stream) {
    const float* X      = (const float*)d_in[0];
    const float* Z      = (const float*)d_in[1];
    const float* Lu_raw = (const float*)d_in[2];
    const float* mu     = (const float*)d_in[3];
    float* out = (float*)d_out;

    if (ws_size >= PACKED_BYTES) {
        float* P = (float*)d_ws;   // packed lower-tri Su
        su_kernel<<<SU_BLOCKS, 256, 0, stream>>>(Lu_raw, P);
        vnngp_kernel<true><<<N_PTS / PTS_PER_BLK, 512, 0, stream>>>(X, Z, mu, P, Lu_raw, out);
    } else {
        vnngp_kernel<false><<<N_PTS / PTS_PER_BLK, 512, 0, stream>>>(X, Z, mu, nullptr, Lu_raw, out);
    }
}

// Round 5
// 259.304 us; speedup vs baseline: 2.7360x; 1.5758x over previous
//
#include <hip/hip_runtime.h>
#include <math.h>

#define N_PTS 65536
#define M_IND 1024
#define KNN 16
#define JITTER 1e-4f

// Packed lower-triangular Su: P[i*(i+1)/2 + j], j <= i.
#define PACKED_FLOATS (M_IND * (M_IND + 1) / 2)               // 524800
#define PACKED_BYTES  ((size_t)PACKED_FLOATS * sizeof(float)) // 2,099,200 B

// ---------------------------------------------------------------------------
// Kernel A: packed Su = tril(Lu Lu^T), Lu = tril(Lu_raw,-1)+diag(exp(diag)).
// 64x64 tiles (136 triangular blocks), 256 threads, 4x4 outputs/thread,
// BK=32 with register-prefetch double buffering (it was latency-bound).
// ---------------------------------------------------------------------------
#define TSU 64
#define BKSU 32
#define SU_BLOCKS 136   // 16*17/2 triangular tiles

__global__ __launch_bounds__(256) void su_kernel(const float* __restrict__ Lu_raw,
                                                 float* __restrict__ P) {
    __shared__ float As[TSU][BKSU + 4];   // +4 pad keeps rows 16B-aligned
    __shared__ float Bs[TSU][BKSU + 4];

    int bid = blockIdx.x;
    int rt = (int)((sqrtf(8.0f * (float)bid + 1.0f) - 1.0f) * 0.5f);
    while ((rt + 1) * (rt + 2) / 2 <= bid) ++rt;
    while (rt * (rt + 1) / 2 > bid) --rt;
    int ct = bid - rt * (rt + 1) / 2;   // ct <= rt
    int i0 = rt * TSU, j0 = ct * TSU;

    int tid = threadIdx.x;
    int tx = tid & 15, ty = tid >> 4;   // 16x16 threads, 4x4 outputs each
    float acc[4][4] = {{0.f}};

    // staging map: e = tid + t*256 -> row e>>3 (0..63), col group e&7 (x4)
    int nchunks = (j0 + TSU) / BKSU;    // k <= min(i,j) <= j0+63

    float4 pa[2], pb[2];
    #pragma unroll
    for (int t = 0; t < 2; ++t) {       // prefetch chunk 0
        int e = tid + t * 256;
        int r = e >> 3, c4 = e & 7;
        pa[t] = *(const float4*)(Lu_raw + (unsigned)(i0 + r) * M_IND + c4 * 4);
        pb[t] = *(const float4*)(Lu_raw + (unsigned)(j0 + r) * M_IND + c4 * 4);
    }

    for (int ch = 0; ch < nchunks; ++ch) {
        int k0 = ch * BKSU;
        // fix (tril/exp-diag) + store prefetched regs to LDS
        #pragma unroll
        for (int t = 0; t < 2; ++t) {
            int e = tid + t * 256;
            int r = e >> 3, c4 = e & 7;
            int gi = i0 + r, gj = j0 + r, gk = k0 + c4 * 4;
            float va[4] = {pa[t].x, pa[t].y, pa[t].z, pa[t].w};
            float vb[4] = {pb[t].x, pb[t].y, pb[t].z, pb[t].w};
            #pragma unroll
            for (int q = 0; q < 4; ++q) {
                int k = gk + q;
                va[q] = (k < gi) ? va[q] : ((k == gi) ? __expf(va[q]) : 0.0f);
                vb[q] = (k < gj) ? vb[q] : ((k == gj) ? __expf(vb[q]) : 0.0f);
            }
            *(float4*)&As[r][c4 * 4] = make_float4(va[0], va[1], va[2], va[3]);
            *(float4*)&Bs[r][c4 * 4] = make_float4(vb[0], vb[1], vb[2], vb[3]);
        }
        __syncthreads();
        if (ch + 1 < nchunks) {         // prefetch next chunk (overlaps compute)
            int kn = (ch + 1) * BKSU;
            #pragma unroll
            for (int t = 0; t < 2; ++t) {
                int e = tid + t * 256;
                int r = e >> 3, c4 = e & 7;
                pa[t] = *(const float4*)(Lu_raw + (unsigned)(i0 + r) * M_IND + kn + c4 * 4);
                pb[t] = *(const float4*)(Lu_raw + (unsigned)(j0 + r) * M_IND + kn + c4 * 4);
            }
        }
        #pragma unroll
        for (int kk = 0; kk < BKSU; ++kk) {
            float a[4], b[4];
            #pragma unroll
            for (int u = 0; u < 4; ++u) a[u] = As[ty + 16 * u][kk];
            #pragma unroll
            for (int v = 0; v < 4; ++v) b[v] = Bs[tx + 16 * v][kk];
            #pragma unroll
            for (int u = 0; u < 4; ++u)
                #pragma unroll
                for (int v = 0; v < 4; ++v)
                    acc[u][v] = fmaf(a[u], b[v], acc[u][v]);
        }
        __syncthreads();
    }

    #pragma unroll
    for (int u = 0; u < 4; ++u) {
        int i = i0 + ty + 16 * u;
        unsigned rowoff = ((unsigned)i * (i + 1)) >> 1;
        #pragma unroll
        for (int v = 0; v < 4; ++v) {
            int j = j0 + tx + 16 * v;
            if (j <= i) P[rowoff + j] = acc[u][v];
        }
    }
}

// ---------------------------------------------------------------------------
// Branchless selection helpers (u64 keys: (f32 dist bits)<<32 | index).
// ---------------------------------------------------------------------------
__device__ __forceinline__ void ce(unsigned long long& x, unsigned long long& y) {
    unsigned long long a = x, b = y;
    bool c = a < b;
    x = c ? a : b;
    y = c ? b : a;
}

// Batcher odd-even mergesort, n=16, 63 compare-exchanges, ascending.
__device__ __forceinline__ void sort16(unsigned long long* a) {
    #pragma unroll
    for (int p = 1; p < 16; p <<= 1)
        #pragma unroll
        for (int k = p; k >= 1; k >>= 1)
            #pragma unroll
            for (int j = k & (p - 1); j + k < 16; j += 2 * k)
                #pragma unroll
                for (int i = 0; i < k; ++i)
                    if (i + j + k < 16)
                        if (((i + j) / (2 * p)) == ((i + j + k) / (2 * p)))
                            ce(a[i + j], a[i + j + k]);
}

// ---------------------------------------------------------------------------
// Kernel B: 4 threads/point branchless chunk-sort selection + shfl_xor quad
// merge + 1-thread/point local GP solve. Block = 512 threads = 128 points.
// __launch_bounds__(512,2): VGPR cap 256 so phase 2's A[136] stays in regs
// (R4's (512,4)=128 cap spilled it -> 60 MB scratch traffic).
// ---------------------------------------------------------------------------
#define PTS_PER_BLK 128

template <bool USE_WS>
__global__ __launch_bounds__(512, 2) void vnngp_kernel(const float* __restrict__ X,
                                                       const float* __restrict__ Z,
                                                       const float* __restrict__ mu,
                                                       const float* __restrict__ P,
                                                       const float* __restrict__ Lu_raw,
                                                       float* __restrict__ out) {
    __shared__ float4 Zs[M_IND];                              // 16 KB
    __shared__ float mus[M_IND];                              // 4 KB
    __shared__ unsigned long long hand[PTS_PER_BLK][KNN + 1]; // 17 KB
    int tid = threadIdx.x;
    for (int r = tid; r < M_IND; r += 512) {
        float zx = Z[r * 3 + 0], zy = Z[r * 3 + 1], zz = Z[r * 3 + 2];
        Zs[r] = make_float4(zx, zy, zz, zx * zx + zy * zy + zz * zz);
        mus[r] = mu[r];
    }
    __syncthreads();

    // ---- Phase 1: branchless top-16 over a 256-candidate stripe ----
    {
        int pt = tid >> 2, sub = tid & 3;
        int n = blockIdx.x * PTS_PER_BLK + pt;
        float x0 = X[n * 3 + 0], x1 = X[n * 3 + 1], x2 = X[n * 3 + 2];
        float xq = x0 * x0 + x1 * x1 + x2 * x2;

        unsigned long long R[KNN];
        #pragma unroll
        for (int j = 0; j < KNN; ++j) R[j] = ~0ULL;

        int mbase = sub << 8;
        int rot = sub * 2;   // bank phase: subs hit disjoint bank quads

        #pragma unroll 1     // keep chunk loop rolled (body ~700 instr)
        for (int c = 0; c < 16; ++c) {
            int base = mbase + (c << 4);
            unsigned long long C[16];
            #pragma unroll
            for (int j = 0; j < 16; ++j) {
                int m = base + ((j + rot) & 15);
                float4 z = Zs[m];
                float dot = fmaf(x0, z.x, fmaf(x1, z.y, x2 * z.z));
                float d = fmaxf(fmaf(-2.0f, dot, xq + z.w), 0.0f);
                C[j] = ((unsigned long long)__float_as_uint(d) << 32) | (unsigned)m;
            }
            sort16(C);
            // R = lowest-16 of (R asc, C asc): reverse-min then bitonic cleanup
            #pragma unroll
            for (int i = 0; i < 16; ++i) {
                unsigned long long b = C[15 - i];
                R[i] = R[i] < b ? R[i] : b;
            }
            #pragma unroll
            for (int d = 8; d >= 1; d >>= 1)
                #pragma unroll
                for (int i = 0; i < 16; ++i)
                    if ((i & d) == 0) ce(R[i], R[i | d]);
        }

        // ---- merge 4 sorted-16 lists within each quad (exact set union) ----
        #pragma unroll
        for (int round = 1; round <= 2; round <<= 1) {
            unsigned long long other[KNN];
            #pragma unroll
            for (int i = 0; i < KNN; ++i)
                other[i] = __shfl_xor(R[i], round, 64);
            #pragma unroll
            for (int i = 0; i < KNN; ++i) {
                unsigned long long b = other[KNN - 1 - i];
                R[i] = R[i] < b ? R[i] : b;
            }
            #pragma unroll
            for (int d = 8; d >= 1; d >>= 1)
                #pragma unroll
                for (int i = 0; i < KNN; ++i)
                    if ((i & d) == 0) ce(R[i], R[i | d]);
        }
        if (sub == 0) {
            #pragma unroll
            for (int i = 0; i < KNN; ++i) hand[pt][i] = R[i];
        }
    }
    __syncthreads();
    if (tid >= PTS_PER_BLK) return;

    // ---- Phase 2: local GP, one thread per point ----
    int n = blockIdx.x * PTS_PER_BLK + tid;
    int idx[KNN];
    float kv[KNN];
    float nx[KNN], ny[KNN], nz[KNN], nq[KNN];
    #pragma unroll
    for (int a = 0; a < KNN; ++a) {
        unsigned long long k = hand[tid][a];
        idx[a] = (int)(k & 0xFFFFFFFFULL);
        float d = __uint_as_float((unsigned)(k >> 32));
        kv[a] = __expf(-0.5f * d);            // lKxz entries
        float4 z = Zs[idx[a]];
        nx[a] = z.x; ny[a] = z.y; nz[a] = z.z; nq[a] = z.w;
    }

    // A = lKzz + JITTER*I (lower tri); lKzz diag carries global jitter from
    // Kzz_j = L L^T -> diag = 1 + 2*JITTER.
    float A[KNN * (KNN + 1) / 2];
    #pragma unroll
    for (int r = 0; r < KNN; ++r) {
        A[r * (r + 1) / 2 + r] = 1.0f + 2.0f * JITTER;
        #pragma unroll
        for (int c = 0; c < r; ++c) {
            float dd = nq[r] + nq[c]
                     - 2.0f * (nx[r] * nx[c] + ny[r] * ny[c] + nz[r] * nz[c]);
            dd = fmaxf(dd, 0.0f);
            A[r * (r + 1) / 2 + c] = __expf(-0.5f * dd);
        }
    }

    // In-place Cholesky; store 1/L[c][c] in the diagonal slot.
    #pragma unroll
    for (int c = 0; c < KNN; ++c) {
        float diag = A[c * (c + 1) / 2 + c];
        #pragma unroll
        for (int k = 0; k < c; ++k) {
            float l = A[c * (c + 1) / 2 + k];
            diag = fmaf(-l, l, diag);
        }
        float s = sqrtf(fmaxf(diag, 1e-12f));
        float rinv = 1.0f / s;
        A[c * (c + 1) / 2 + c] = rinv;
        #pragma unroll
        for (int r = c + 1; r < KNN; ++r) {
            float v = A[r * (r + 1) / 2 + c];
            #pragma unroll
            for (int k = 0; k < c; ++k)
                v = fmaf(-A[r * (r + 1) / 2 + k], A[c * (c + 1) / 2 + k], v);
            A[r * (r + 1) / 2 + c] = v * rinv;
        }
    }

    // Solve A w = kv (forward then backward).
    float w[KNN];
    #pragma unroll
    for (int r = 0; r < KNN; ++r) {
        float v = kv[r];
        #pragma unroll
        for (int c = 0; c < r; ++c) v = fmaf(-A[r * (r + 1) / 2 + c], w[c], v);
        w[r] = v * A[r * (r + 1) / 2 + r];
    }
    #pragma unroll
    for (int r = KNN - 1; r >= 0; --r) {
        float v = w[r];
        #pragma unroll
        for (int c = r + 1; c < KNN; ++c) v = fmaf(-A[c * (c + 1) / 2 + r], w[c], v);
        w[r] = v * A[r * (r + 1) / 2 + r];
    }

    // W lKzz W^T = w.k - JITTER*||w||^2   (A w = k, lKzz = A - JITTER*I)
    float wk = 0.f, ww = 0.f, mean = 0.f;
    #pragma unroll
    for (int a = 0; a < KNN; ++a) {
        wk = fmaf(w[a], kv[a], wk);
        ww = fmaf(w[a], w[a], ww);
        mean = fmaf(w[a], mus[idx[a]], mean);
    }

    // qs = w^T Su[idx,idx] w
    float qs = 0.f;
    if (USE_WS) {
        #pragma unroll
        for (int r = 0; r < KNN; ++r) {
            int a = idx[r];
            float wr = w[r];
            float rowacc = 0.f;
            #pragma unroll
            for (int c = 0; c < r; ++c) {
                int b = idx[c];
                int hi = a > b ? a : b;
                int lo = a > b ? b : a;
                rowacc = fmaf(w[c], P[((unsigned)hi * (hi + 1) >> 1) + lo], rowacc);
            }
            qs = fmaf(wr, fmaf(wr, P[((unsigned)a * (a + 1) >> 1) + a], 2.0f * rowacc), qs);
        }
    } else {
        // On-demand fallback: qs = sum_k (sum_a w_a * Lu[idx_a, k])^2
        int si[KNN]; float sw[KNN];
        #pragma unroll
        for (int a = 0; a < KNN; ++a) { si[a] = idx[a]; sw[a] = w[a]; }
        #pragma unroll
        for (int a = 1; a < KNN; ++a) {
            int iv = si[a]; float wv = sw[a];
            int b = a - 1;
            while (b >= 0 && si[b] > iv) { si[b + 1] = si[b]; sw[b + 1] = sw[b]; --b; }
            si[b + 1] = iv; sw[b + 1] = wv;
        }
        int s = 0;
        int kend = si[KNN - 1];
        for (int k = 0; k <= kend; ++k) {
            float v = 0.f;
            if (s < KNN && si[s] == k) {
                v = sw[s] * __expf(Lu_raw[(unsigned)k * M_IND + k]);
                ++s;
            }
            for (int a = s; a < KNN; ++a)
                v = fmaf(sw[a], Lu_raw[(unsigned)si[a] * M_IND + k], v);
            qs = fmaf(v, v, qs);
        }
    }

    float cov = 1.0f - (wk - JITTER * ww) + qs;
    float sd = sqrtf(fmaxf(cov, 0.05f));
    out[n] = mean;
    out[N_PTS + n] = sd;
}

// ---------------------------------------------------------------------------
extern "C" void kernel_launch(void* const* d_in, const int* in_sizes, int n_in,
                              void* d_out, int out_size, void* d_ws, size_t ws_size,
                              hipStream_t stream) {
    const float* X      = (const float*)d_in[0];
    const float* Z      = (const float*)d_in[1];
    const float* Lu_raw = (const float*)d_in[2];
    const float* mu     = (const float*)d_in[3];
    float* out = (float*)d_out;

    if (ws_size >= PACKED_BYTES) {
        float* P = (float*)d_ws;   // packed lower-tri Su
        su_kernel<<<SU_BLOCKS, 256, 0, stream>>>(Lu_raw, P);
        vnngp_kernel<true><<<N_PTS / PTS_PER_BLK, 512, 0, stream>>>(X, Z, mu, P, Lu_raw, out);
    } else {
        vnngp_kernel<false><<<N_PTS / PTS_PER_BLK, 512, 0, stream>>>(X, Z, mu, nullptr, Lu_raw, out);
    }
}